// Round 6
// baseline (73.251 us; speedup 1.0000x reference)
//
#include <hip/hip_runtime.h>
#include <math.h>

#define Bb 128
#define Ee 256
#define Mm 64
#define Cc 5
#define NTOT (Bb*Mm*Ee)   // 2097152
#define BE  (Bb*Ee)       // 32768
#define EPS 1e-5f
#define L2E2 2.8853900817779268f   // 2*log2(e)

#if __has_builtin(__builtin_amdgcn_exp2f)
#define EXP2(x) __builtin_amdgcn_exp2f(x)
#else
#define EXP2(x) exp2f(x)
#endif
#define RCP(x) __builtin_amdgcn_rcpf(x)

// tanh with pre-scaled (by 2*log2e) weights: 1 - 2/(2^(x*w+b+h*u)+1).
__device__ __forceinline__ float tanh_step(float x, float w, float b, float u, float h) {
    float t = __builtin_fmaf(x, w, b);
    t = __builtin_fmaf(h, u, t);
    float r = RCP(EXP2(t) + 1.0f);
    return __builtin_fmaf(-2.0f, r, 1.0f);
}

__device__ __forceinline__ unsigned short f32_to_bf16_rne(float f) {
    unsigned u = __float_as_uint(f);
    unsigned r = (u + 0x7fffu + ((u >> 16) & 1u)) >> 16;
    return (unsigned short)r;
}
__device__ __forceinline__ float bf16_to_f32(unsigned short s) {
    return __uint_as_float(((unsigned)s) << 16);
}

// ---------------------------------------------------------------------------
// Kernel 1: per-sample scalar RNNs over T=4/8/16 + 1x3 conv fusion.
// (Unchanged from round 5 — bench-proven; ~5.6 TB/s effective, near BW wall.)
// Block 0 thread 0 also re-zeros the k_tail barrier counter (stream-ordered).
// ---------------------------------------------------------------------------
__global__ __launch_bounds__(256, 8) void k_rnn1(
    const float* __restrict__ a0, const float* __restrict__ a1,
    const float* __restrict__ a2,
    const float* __restrict__ wih, const float* __restrict__ whh,
    const float* __restrict__ bih, const float* __restrict__ bhh,
    const float* __restrict__ cw,  const float* __restrict__ cb,
    unsigned short* __restrict__ fusion, int* __restrict__ ctr)
{
    int t = blockIdx.x * blockDim.x + threadIdx.x;
    if (t == 0) *ctr = 0;   // barrier counter for k_tail (next kernel in stream)

    float w0 = wih[0] * L2E2, w1 = wih[1] * L2E2, w2 = wih[2] * L2E2;
    float u0 = whh[0] * L2E2, u1 = whh[1] * L2E2, u2 = whh[2] * L2E2;
    float b0 = (bih[0] + bhh[0]) * L2E2;
    float b1 = (bih[1] + bhh[1]) * L2E2;
    float b2 = (bih[2] + bhh[2]) * L2E2;
    float c0 = cw[0], c1 = cw[1], c2 = cw[2], cbias = cb[0];

    #pragma unroll
    for (int s = 0; s < 2; ++s) {
        int n = t + s * (NTOT / 2);

        // scale 0: T=4
        float4 x0 = ((const float4*)a0)[n];
        float h0 = tanh_step(x0.x, w0, b0, u0, 0.0f);
        h0 = tanh_step(x0.y, w0, b0, u0, h0);
        h0 = tanh_step(x0.z, w0, b0, u0, h0);
        h0 = tanh_step(x0.w, w0, b0, u0, h0);

        // scale 1: T=8
        float4 y0 = ((const float4*)a1)[2*n + 0];
        float4 y1 = ((const float4*)a1)[2*n + 1];
        float h1 = tanh_step(y0.x, w1, b1, u1, 0.0f);
        h1 = tanh_step(y0.y, w1, b1, u1, h1);
        h1 = tanh_step(y0.z, w1, b1, u1, h1);
        h1 = tanh_step(y0.w, w1, b1, u1, h1);
        h1 = tanh_step(y1.x, w1, b1, u1, h1);
        h1 = tanh_step(y1.y, w1, b1, u1, h1);
        h1 = tanh_step(y1.z, w1, b1, u1, h1);
        h1 = tanh_step(y1.w, w1, b1, u1, h1);

        // scale 2: T=16
        float h2 = 0.0f;
        #pragma unroll
        for (int q = 0; q < 4; ++q) {
            float4 z = ((const float4*)a2)[4*n + q];
            h2 = tanh_step(z.x, w2, b2, u2, h2);
            h2 = tanh_step(z.y, w2, b2, u2, h2);
            h2 = tanh_step(z.z, w2, b2, u2, h2);
            h2 = tanh_step(z.w, w2, b2, u2, h2);
        }

        float f = h0 * c0 + h1 * c1 + h2 * c2 + cbias;

        int e = n & (Ee - 1);
        int m = (n >> 8) & (Mm - 1);
        int b = n >> 14;
        fusion[(m << 15) + (b << 8) + e] = f32_to_bf16_rne(f);
    }
}

// ---------------------------------------------------------------------------
// Kernel 2 (fused tail): rnn2 over m  ->  grid barrier  ->  BN stats + norm
// + ReLU + (E->C) linear + softmax. 128 blocks (block = batch row b), all
// co-resident on 256 CUs, so the fence+counter barrier cannot deadlock.
// ---------------------------------------------------------------------------
__global__ __launch_bounds__(256) void k_tail(
    const unsigned short* __restrict__ fusion,
    const float* __restrict__ w, const float* __restrict__ u,
    const float* __restrict__ bi, const float* __restrict__ bh,
    const float* __restrict__ gamma, const float* __restrict__ beta,
    const float* __restrict__ fw, const float* __restrict__ fb,
    float* __restrict__ feat, int* __restrict__ ctr,
    float* __restrict__ out)
{
    const int b = blockIdx.x;
    const int e = threadIdx.x;
    const int j = (b << 8) + e;

    // ---- phase 1: second RNN over m (dense 128B/wave bf16 loads, L2-hot) ----
    float wv = w[0] * L2E2, uv = u[0] * L2E2, bb0 = (bi[0] + bh[0]) * L2E2;
    float h = 0.0f;
    #pragma unroll 16
    for (int m = 0; m < Mm; ++m) {
        float x = bf16_to_f32(fusion[m * BE + j]);
        h = tanh_step(x, wv, bb0, uv, h);
    }
    feat[j] = h;

    // ---- grid barrier (release: flush L2 so other XCDs see feat) ----
    __threadfence();
    __syncthreads();
    if (e == 0) {
        atomicAdd(ctr, 1);
        while (atomicAdd(ctr, 0) < Bb) { __builtin_amdgcn_s_sleep(8); }
    }
    __syncthreads();
    __threadfence();   // acquire: invalidate stale lines before reading feat

    // ---- phase 2: batch stats for channel e (biased variance) ----
    float s = 0.0f, s2 = 0.0f;
    #pragma unroll 8
    for (int bb = 0; bb < Bb; ++bb) {
        float v = feat[bb * Ee + e];
        s  += v;
        s2 += v * v;
    }
    float mean = s * (1.0f / Bb);
    float var  = s2 * (1.0f / Bb) - mean * mean;
    float a = gamma[e] * rsqrtf(var + EPS);
    float shift = beta[e] - mean * a;

    float v = fmaxf(h * a + shift, 0.0f);   // own feat from register

    float p[Cc];
    #pragma unroll
    for (int c = 0; c < Cc; ++c) p[c] = v * fw[c * Ee + e];

    #pragma unroll
    for (int off = 32; off > 0; off >>= 1) {
        #pragma unroll
        for (int c = 0; c < Cc; ++c) p[c] += __shfl_down(p[c], off);
    }

    __shared__ float lds[4][Cc];
    int wave = e >> 6, lane = e & 63;
    if (lane == 0) {
        #pragma unroll
        for (int c = 0; c < Cc; ++c) lds[wave][c] = p[c];
    }
    __syncthreads();

    if (e == 0) {
        float lg[Cc];
        #pragma unroll
        for (int c = 0; c < Cc; ++c)
            lg[c] = lds[0][c] + lds[1][c] + lds[2][c] + lds[3][c] + fb[c];
        float mx = lg[0];
        #pragma unroll
        for (int c = 1; c < Cc; ++c) mx = fmaxf(mx, lg[c]);
        float se = 0.0f;
        #pragma unroll
        for (int c = 0; c < Cc; ++c) { lg[c] = EXP2((lg[c] - mx) * 1.4426950408889634f); se += lg[c]; }
        float inv = RCP(se);
        #pragma unroll
        for (int c = 0; c < Cc; ++c) out[b * Cc + c] = lg[c] * inv;
    }
}

extern "C" void kernel_launch(void* const* d_in, const int* in_sizes, int n_in,
                              void* d_out, int out_size, void* d_ws, size_t ws_size,
                              hipStream_t stream) {
    const float* a0       = (const float*)d_in[0];
    const float* a1       = (const float*)d_in[1];
    const float* a2       = (const float*)d_in[2];
    const float* rnn1_wih = (const float*)d_in[3];
    const float* rnn1_whh = (const float*)d_in[4];
    const float* rnn1_bih = (const float*)d_in[5];
    const float* rnn1_bhh = (const float*)d_in[6];
    const float* conv_w   = (const float*)d_in[7];
    const float* conv_b   = (const float*)d_in[8];
    const float* rnn2_wih = (const float*)d_in[9];
    const float* rnn2_whh = (const float*)d_in[10];
    const float* rnn2_bih = (const float*)d_in[11];
    const float* rnn2_bhh = (const float*)d_in[12];
    const float* gamma    = (const float*)d_in[13];
    const float* beta     = (const float*)d_in[14];
    const float* fnn_w    = (const float*)d_in[15];
    const float* fnn_b    = (const float*)d_in[16];

    float* out = (float*)d_out;

    // workspace layout
    char* ws = (char*)d_ws;
    unsigned short* fusion = (unsigned short*)ws;              // M*BE bf16 = 4 MB
    float* feat = (float*)(ws + (size_t)Mm * BE * 2);          // BE floats = 128 KB
    int*   ctr  = (int*)(ws + (size_t)Mm * BE * 2 + (size_t)BE * 4);

    k_rnn1<<<NTOT / 2 / 256, 256, 0, stream>>>(a0, a1, a2,
        rnn1_wih, rnn1_whh, rnn1_bih, rnn1_bhh, conv_w, conv_b, fusion, ctr);
    k_tail<<<Bb, 256, 0, stream>>>(fusion,
        rnn2_wih, rnn2_whh, rnn2_bih, rnn2_bhh,
        gamma, beta, fnn_w, fnn_b, feat, ctr, out);
}

// Round 7
// 51.632 us; speedup vs baseline: 1.4187x; 1.4187x over previous
//
#include <hip/hip_runtime.h>
#include <math.h>

#define Bb 128
#define Ee 256
#define Mm 64
#define Cc 5
#define NTOT (Bb*Mm*Ee)   // 2097152
#define BE  (Bb*Ee)       // 32768
#define EPS 1e-5f
#define L2E2 2.8853900817779268f   // 2*log2(e)

#if __has_builtin(__builtin_amdgcn_exp2f)
#define EXP2(x) __builtin_amdgcn_exp2f(x)
#else
#define EXP2(x) exp2f(x)
#endif
#define RCP(x) __builtin_amdgcn_rcpf(x)

// tanh with pre-scaled (by 2*log2e) weights: 1 - 2/(2^(x*w+b+h*u)+1).
__device__ __forceinline__ float tanh_step(float x, float w, float b, float u, float h) {
    float t = __builtin_fmaf(x, w, b);
    t = __builtin_fmaf(h, u, t);
    float r = RCP(EXP2(t) + 1.0f);
    return __builtin_fmaf(-2.0f, r, 1.0f);
}

__device__ __forceinline__ unsigned short f32_to_bf16_rne(float f) {
    unsigned u = __float_as_uint(f);
    unsigned r = (u + 0x7fffu + ((u >> 16) & 1u)) >> 16;
    return (unsigned short)r;
}
__device__ __forceinline__ float bf16_to_f32(unsigned short s) {
    return __uint_as_float(((unsigned)s) << 16);
}

// ---------------------------------------------------------------------------
// Kernel 1: per-sample scalar RNNs over T=4/8/16 + 1x3 conv fusion.
// All 14 float4 loads (2 samples x 7 chunks) issued UP FRONT into registers
// so they are simultaneously in flight (MLP ~14/thread); the 6 independent
// tanh chains then run from registers. __launch_bounds__(256,6): VGPR cap
// ~85 (needs ~56 for load data), 6 blocks/CU = 75% occupancy.
// fusion stored bf16 [m][b*E+e] so k_rnn2's per-step loads are coalesced.
// ---------------------------------------------------------------------------
__global__ __launch_bounds__(256, 6) void k_rnn1(
    const float* __restrict__ a0, const float* __restrict__ a1,
    const float* __restrict__ a2,
    const float* __restrict__ wih, const float* __restrict__ whh,
    const float* __restrict__ bih, const float* __restrict__ bhh,
    const float* __restrict__ cw,  const float* __restrict__ cb,
    unsigned short* __restrict__ fusion)
{
    const int t = blockIdx.x * blockDim.x + threadIdx.x;
    const int n0 = t;
    const int n1 = t + NTOT / 2;

    const float4* __restrict__ A0 = (const float4*)a0;
    const float4* __restrict__ A1 = (const float4*)a1;
    const float4* __restrict__ A2 = (const float4*)a2;

    // ---- issue ALL loads first (14 independent float4 = 224B/thread) ----
    float4 xa  = A0[n0];
    float4 xb  = A0[n1];
    float4 ya0 = A1[2*n0 + 0], ya1 = A1[2*n0 + 1];
    float4 yb0 = A1[2*n1 + 0], yb1 = A1[2*n1 + 1];
    float4 za0 = A2[4*n0 + 0], za1 = A2[4*n0 + 1];
    float4 za2 = A2[4*n0 + 2], za3 = A2[4*n0 + 3];
    float4 zb0 = A2[4*n1 + 0], zb1 = A2[4*n1 + 1];
    float4 zb2 = A2[4*n1 + 2], zb3 = A2[4*n1 + 3];

    // uniform pre-scaled constants (SGPRs)
    float w0 = wih[0] * L2E2, w1 = wih[1] * L2E2, w2 = wih[2] * L2E2;
    float u0 = whh[0] * L2E2, u1 = whh[1] * L2E2, u2 = whh[2] * L2E2;
    float b0 = (bih[0] + bhh[0]) * L2E2;
    float b1 = (bih[1] + bhh[1]) * L2E2;
    float b2 = (bih[2] + bhh[2]) * L2E2;
    float c0 = cw[0], c1 = cw[1], c2 = cw[2], cbias = cb[0];

    // ---- 6 independent tanh chains (ILP) ----
    float h0a = tanh_step(xa.x, w0, b0, u0, 0.0f);
    float h0b = tanh_step(xb.x, w0, b0, u0, 0.0f);
    h0a = tanh_step(xa.y, w0, b0, u0, h0a);
    h0b = tanh_step(xb.y, w0, b0, u0, h0b);
    h0a = tanh_step(xa.z, w0, b0, u0, h0a);
    h0b = tanh_step(xb.z, w0, b0, u0, h0b);
    h0a = tanh_step(xa.w, w0, b0, u0, h0a);
    h0b = tanh_step(xb.w, w0, b0, u0, h0b);

    float h1a = tanh_step(ya0.x, w1, b1, u1, 0.0f);
    float h1b = tanh_step(yb0.x, w1, b1, u1, 0.0f);
    h1a = tanh_step(ya0.y, w1, b1, u1, h1a);
    h1b = tanh_step(yb0.y, w1, b1, u1, h1b);
    h1a = tanh_step(ya0.z, w1, b1, u1, h1a);
    h1b = tanh_step(yb0.z, w1, b1, u1, h1b);
    h1a = tanh_step(ya0.w, w1, b1, u1, h1a);
    h1b = tanh_step(yb0.w, w1, b1, u1, h1b);
    h1a = tanh_step(ya1.x, w1, b1, u1, h1a);
    h1b = tanh_step(yb1.x, w1, b1, u1, h1b);
    h1a = tanh_step(ya1.y, w1, b1, u1, h1a);
    h1b = tanh_step(yb1.y, w1, b1, u1, h1b);
    h1a = tanh_step(ya1.z, w1, b1, u1, h1a);
    h1b = tanh_step(yb1.z, w1, b1, u1, h1b);
    h1a = tanh_step(ya1.w, w1, b1, u1, h1a);
    h1b = tanh_step(yb1.w, w1, b1, u1, h1b);

    float h2a = tanh_step(za0.x, w2, b2, u2, 0.0f);
    float h2b = tanh_step(zb0.x, w2, b2, u2, 0.0f);
    h2a = tanh_step(za0.y, w2, b2, u2, h2a);
    h2b = tanh_step(zb0.y, w2, b2, u2, h2b);
    h2a = tanh_step(za0.z, w2, b2, u2, h2a);
    h2b = tanh_step(zb0.z, w2, b2, u2, h2b);
    h2a = tanh_step(za0.w, w2, b2, u2, h2a);
    h2b = tanh_step(zb0.w, w2, b2, u2, h2b);
    h2a = tanh_step(za1.x, w2, b2, u2, h2a);
    h2b = tanh_step(zb1.x, w2, b2, u2, h2b);
    h2a = tanh_step(za1.y, w2, b2, u2, h2a);
    h2b = tanh_step(zb1.y, w2, b2, u2, h2b);
    h2a = tanh_step(za1.z, w2, b2, u2, h2a);
    h2b = tanh_step(zb1.z, w2, b2, u2, h2b);
    h2a = tanh_step(za1.w, w2, b2, u2, h2a);
    h2b = tanh_step(zb1.w, w2, b2, u2, h2b);
    h2a = tanh_step(za2.x, w2, b2, u2, h2a);
    h2b = tanh_step(zb2.x, w2, b2, u2, h2b);
    h2a = tanh_step(za2.y, w2, b2, u2, h2a);
    h2b = tanh_step(zb2.y, w2, b2, u2, h2b);
    h2a = tanh_step(za2.z, w2, b2, u2, h2a);
    h2b = tanh_step(zb2.z, w2, b2, u2, h2b);
    h2a = tanh_step(za2.w, w2, b2, u2, h2a);
    h2b = tanh_step(zb2.w, w2, b2, u2, h2b);
    h2a = tanh_step(za3.x, w2, b2, u2, h2a);
    h2b = tanh_step(zb3.x, w2, b2, u2, h2b);
    h2a = tanh_step(za3.y, w2, b2, u2, h2a);
    h2b = tanh_step(zb3.y, w2, b2, u2, h2b);
    h2a = tanh_step(za3.z, w2, b2, u2, h2a);
    h2b = tanh_step(zb3.z, w2, b2, u2, h2b);
    h2a = tanh_step(za3.w, w2, b2, u2, h2a);
    h2b = tanh_step(zb3.w, w2, b2, u2, h2b);

    float fa = h0a * c0 + h1a * c1 + h2a * c2 + cbias;
    float fb = h0b * c0 + h1b * c1 + h2b * c2 + cbias;

    // n = (b<<14) | (m<<8) | e
    {
        int e = n0 & (Ee - 1), m = (n0 >> 8) & (Mm - 1), b = n0 >> 14;
        fusion[(m << 15) + (b << 8) + e] = f32_to_bf16_rne(fa);
    }
    {
        int e = n1 & (Ee - 1), m = (n1 >> 8) & (Mm - 1), b = n1 >> 14;
        fusion[(m << 15) + (b << 8) + e] = f32_to_bf16_rne(fb);
    }
}

// ---------------------------------------------------------------------------
// Kernel 2: second scalar RNN over m for each (b,e) lane (bf16 input).
// ---------------------------------------------------------------------------
__global__ __launch_bounds__(256) void k_rnn2(
    const unsigned short* __restrict__ fusion,
    const float* __restrict__ w, const float* __restrict__ u,
    const float* __restrict__ bi, const float* __restrict__ bh,
    float* __restrict__ feat)
{
    int j = blockIdx.x * blockDim.x + threadIdx.x;   // b*E + e
    float wv = w[0] * L2E2, uv = u[0] * L2E2, bb = (bi[0] + bh[0]) * L2E2;
    float h = 0.0f;
    #pragma unroll 16
    for (int m = 0; m < Mm; ++m) {
        float x = bf16_to_f32(fusion[m * BE + j]);
        h = tanh_step(x, wv, bb, uv, h);
    }
    feat[j] = h;
}

// ---------------------------------------------------------------------------
// Kernel 3: fused BatchNorm stats + norm + ReLU + (E->C) linear + softmax.
// One block per batch row; stats recomputed per block (feat is L2-hot).
// ---------------------------------------------------------------------------
__global__ __launch_bounds__(256) void k_head(
    const float* __restrict__ feat,
    const float* __restrict__ gamma, const float* __restrict__ beta,
    const float* __restrict__ fw, const float* __restrict__ fb,
    float* __restrict__ out)
{
    int b = blockIdx.x;
    int e = threadIdx.x;

    float s = 0.0f, s2 = 0.0f;
    #pragma unroll 8
    for (int bb = 0; bb < Bb; ++bb) {
        float v = feat[bb * Ee + e];
        s  += v;
        s2 += v * v;
    }
    float mean = s * (1.0f / Bb);
    float var  = s2 * (1.0f / Bb) - mean * mean;
    float a = gamma[e] * rsqrtf(var + EPS);
    float shift = beta[e] - mean * a;

    float v = fmaxf(feat[b * Ee + e] * a + shift, 0.0f);

    float p[Cc];
    #pragma unroll
    for (int c = 0; c < Cc; ++c) p[c] = v * fw[c * Ee + e];

    #pragma unroll
    for (int off = 32; off > 0; off >>= 1) {
        #pragma unroll
        for (int c = 0; c < Cc; ++c) p[c] += __shfl_down(p[c], off);
    }

    __shared__ float lds[4][Cc];
    int wave = e >> 6, lane = e & 63;
    if (lane == 0) {
        #pragma unroll
        for (int c = 0; c < Cc; ++c) lds[wave][c] = p[c];
    }
    __syncthreads();

    if (e == 0) {
        float lg[Cc];
        #pragma unroll
        for (int c = 0; c < Cc; ++c)
            lg[c] = lds[0][c] + lds[1][c] + lds[2][c] + lds[3][c] + fb[c];
        float mx = lg[0];
        #pragma unroll
        for (int c = 1; c < Cc; ++c) mx = fmaxf(mx, lg[c]);
        float se = 0.0f;
        #pragma unroll
        for (int c = 0; c < Cc; ++c) { lg[c] = EXP2((lg[c] - mx) * 1.4426950408889634f); se += lg[c]; }
        float inv = RCP(se);
        #pragma unroll
        for (int c = 0; c < Cc; ++c) out[b * Cc + c] = lg[c] * inv;
    }
}

extern "C" void kernel_launch(void* const* d_in, const int* in_sizes, int n_in,
                              void* d_out, int out_size, void* d_ws, size_t ws_size,
                              hipStream_t stream) {
    const float* a0       = (const float*)d_in[0];
    const float* a1       = (const float*)d_in[1];
    const float* a2       = (const float*)d_in[2];
    const float* rnn1_wih = (const float*)d_in[3];
    const float* rnn1_whh = (const float*)d_in[4];
    const float* rnn1_bih = (const float*)d_in[5];
    const float* rnn1_bhh = (const float*)d_in[6];
    const float* conv_w   = (const float*)d_in[7];
    const float* conv_b   = (const float*)d_in[8];
    const float* rnn2_wih = (const float*)d_in[9];
    const float* rnn2_whh = (const float*)d_in[10];
    const float* rnn2_bih = (const float*)d_in[11];
    const float* rnn2_bhh = (const float*)d_in[12];
    const float* gamma    = (const float*)d_in[13];
    const float* beta     = (const float*)d_in[14];
    const float* fnn_w    = (const float*)d_in[15];
    const float* fnn_b    = (const float*)d_in[16];

    float* out = (float*)d_out;

    // workspace layout
    char* ws = (char*)d_ws;
    unsigned short* fusion = (unsigned short*)ws;              // M*BE bf16 = 4 MB
    float* feat = (float*)(ws + (size_t)Mm * BE * 2);          // BE floats = 128 KB

    k_rnn1<<<NTOT / 2 / 256, 256, 0, stream>>>(a0, a1, a2,
        rnn1_wih, rnn1_whh, rnn1_bih, rnn1_bhh, conv_w, conv_b, fusion);
    k_rnn2<<<BE / 256, 256, 0, stream>>>(fusion,
        rnn2_wih, rnn2_whh, rnn2_bih, rnn2_bhh, feat);
    k_head<<<Bb, 256, 0, stream>>>(feat, gamma, beta, fnn_w, fnn_b, out);
}

// Round 9
// 47.992 us; speedup vs baseline: 1.5263x; 1.0759x over previous
//
#include <hip/hip_runtime.h>
#include <math.h>

#define Bb 128
#define Ee 256
#define Mm 64
#define Cc 5
#define NTOT (Bb*Mm*Ee)   // 2097152
#define BE  (Bb*Ee)       // 32768
#define EPS 1e-5f
#define L2E2 2.8853900817779268f   // 2*log2(e)

#if __has_builtin(__builtin_amdgcn_exp2f)
#define EXP2(x) __builtin_amdgcn_exp2f(x)
#else
#define EXP2(x) exp2f(x)
#endif
#define RCP(x) __builtin_amdgcn_rcpf(x)

// tanh with pre-scaled (by 2*log2e) weights: 1 - 2/(2^(x*w+b+h*u)+1).
__device__ __forceinline__ float tanh_step(float x, float w, float b, float u, float h) {
    float t = __builtin_fmaf(x, w, b);
    t = __builtin_fmaf(h, u, t);
    float r = RCP(EXP2(t) + 1.0f);
    return __builtin_fmaf(-2.0f, r, 1.0f);
}

__device__ __forceinline__ unsigned short f32_to_bf16_rne(float f) {
    unsigned u = __float_as_uint(f);
    unsigned r = (u + 0x7fffu + ((u >> 16) & 1u)) >> 16;
    return (unsigned short)r;
}
__device__ __forceinline__ float bf16_to_f32(unsigned short s) {
    return __uint_as_float(((unsigned)s) << 16);
}

// ---------------------------------------------------------------------------
// Kernel 1: per-sample scalar RNNs over T=4/8/16 + 1x3 conv fusion.
// EXACT round-5 structure (bench-proven; at the memory-service wall).
// Block 0 re-zeroes the stats scratch each call (stream-ordered: kernel
// boundary makes it visible to k_rnn2's atomics -> deterministic).
// fusion stored bf16 [m][b*E+e] so k_rnn2's per-step loads are coalesced.
// ---------------------------------------------------------------------------
__global__ __launch_bounds__(256, 8) void k_rnn1(
    const float* __restrict__ a0, const float* __restrict__ a1,
    const float* __restrict__ a2,
    const float* __restrict__ wih, const float* __restrict__ whh,
    const float* __restrict__ bih, const float* __restrict__ bhh,
    const float* __restrict__ cw,  const float* __restrict__ cb,
    unsigned short* __restrict__ fusion,
    float* __restrict__ stats)
{
    int t = blockIdx.x * blockDim.x + threadIdx.x;

    if (blockIdx.x == 0) {
        stats[threadIdx.x]       = 0.0f;   // sum[e]
        stats[256 + threadIdx.x] = 0.0f;   // sumsq[e]
    }

    float w0 = wih[0] * L2E2, w1 = wih[1] * L2E2, w2 = wih[2] * L2E2;
    float u0 = whh[0] * L2E2, u1 = whh[1] * L2E2, u2 = whh[2] * L2E2;
    float b0 = (bih[0] + bhh[0]) * L2E2;
    float b1 = (bih[1] + bhh[1]) * L2E2;
    float b2 = (bih[2] + bhh[2]) * L2E2;
    float c0 = cw[0], c1 = cw[1], c2 = cw[2], cbias = cb[0];

    #pragma unroll
    for (int s = 0; s < 2; ++s) {
        int n = t + s * (NTOT / 2);

        // scale 0: T=4
        float4 x0 = ((const float4*)a0)[n];
        float h0 = tanh_step(x0.x, w0, b0, u0, 0.0f);
        h0 = tanh_step(x0.y, w0, b0, u0, h0);
        h0 = tanh_step(x0.z, w0, b0, u0, h0);
        h0 = tanh_step(x0.w, w0, b0, u0, h0);

        // scale 1: T=8
        float4 y0 = ((const float4*)a1)[2*n + 0];
        float4 y1 = ((const float4*)a1)[2*n + 1];
        float h1 = tanh_step(y0.x, w1, b1, u1, 0.0f);
        h1 = tanh_step(y0.y, w1, b1, u1, h1);
        h1 = tanh_step(y0.z, w1, b1, u1, h1);
        h1 = tanh_step(y0.w, w1, b1, u1, h1);
        h1 = tanh_step(y1.x, w1, b1, u1, h1);
        h1 = tanh_step(y1.y, w1, b1, u1, h1);
        h1 = tanh_step(y1.z, w1, b1, u1, h1);
        h1 = tanh_step(y1.w, w1, b1, u1, h1);

        // scale 2: T=16
        float h2 = 0.0f;
        #pragma unroll
        for (int q = 0; q < 4; ++q) {
            float4 z = ((const float4*)a2)[4*n + q];
            h2 = tanh_step(z.x, w2, b2, u2, h2);
            h2 = tanh_step(z.y, w2, b2, u2, h2);
            h2 = tanh_step(z.z, w2, b2, u2, h2);
            h2 = tanh_step(z.w, w2, b2, u2, h2);
        }

        float f = h0 * c0 + h1 * c1 + h2 * c2 + cbias;

        int e = n & (Ee - 1);
        int m = (n >> 8) & (Mm - 1);
        int b = n >> 14;
        fusion[(m << 15) + (b << 8) + e] = f32_to_bf16_rne(f);
    }
}

// ---------------------------------------------------------------------------
// Kernel 2: second scalar RNN over m for each (b,e) lane (bf16 input),
// PLUS per-channel BN statistics contribution via device-scope atomicAdd.
// Ordering/visibility for the consumer comes from the KERNEL BOUNDARY
// (no fence, no spin -- the round-6/round-8 failure modes are avoided).
// block = batch row b, thread = channel e.
// ---------------------------------------------------------------------------
__global__ __launch_bounds__(256) void k_rnn2(
    const unsigned short* __restrict__ fusion,
    const float* __restrict__ w, const float* __restrict__ u,
    const float* __restrict__ bi, const float* __restrict__ bh,
    float* __restrict__ feat, float* __restrict__ stats)
{
    const int e = threadIdx.x;
    const int j = (blockIdx.x << 8) + e;

    float wv = w[0] * L2E2, uv = u[0] * L2E2, bb = (bi[0] + bh[0]) * L2E2;
    float h = 0.0f;
    #pragma unroll 16
    for (int m = 0; m < Mm; ++m) {
        float x = bf16_to_f32(fusion[m * BE + j]);
        h = tanh_step(x, wv, bb, uv, h);
    }
    feat[j] = h;
    atomicAdd(&stats[e], h);
    atomicAdd(&stats[256 + e], h * h);
}

// ---------------------------------------------------------------------------
// Kernel 3: BN (stats precomputed) + ReLU + (E->C) linear + softmax.
// One block per batch row; no stats loop -- reads stats[] directly.
// ---------------------------------------------------------------------------
__global__ __launch_bounds__(256) void k_head(
    const float* __restrict__ feat, const float* __restrict__ stats,
    const float* __restrict__ gamma, const float* __restrict__ beta,
    const float* __restrict__ fw, const float* __restrict__ fb,
    float* __restrict__ out)
{
    int b = blockIdx.x;
    int e = threadIdx.x;

    float s  = stats[e];
    float s2 = stats[256 + e];
    float mean = s * (1.0f / Bb);
    float var  = s2 * (1.0f / Bb) - mean * mean;
    float a = gamma[e] * rsqrtf(var + EPS);
    float shift = beta[e] - mean * a;

    float v = fmaxf(feat[(b << 8) + e] * a + shift, 0.0f);

    float p[Cc];
    #pragma unroll
    for (int c = 0; c < Cc; ++c) p[c] = v * fw[c * Ee + e];

    #pragma unroll
    for (int off = 32; off > 0; off >>= 1) {
        #pragma unroll
        for (int c = 0; c < Cc; ++c) p[c] += __shfl_down(p[c], off);
    }

    __shared__ float lds[4][Cc];
    int wave = e >> 6, lane = e & 63;
    if (lane == 0) {
        #pragma unroll
        for (int c = 0; c < Cc; ++c) lds[wave][c] = p[c];
    }
    __syncthreads();

    if (e == 0) {
        float lg[Cc];
        #pragma unroll
        for (int c = 0; c < Cc; ++c)
            lg[c] = lds[0][c] + lds[1][c] + lds[2][c] + lds[3][c] + fb[c];
        float mx = lg[0];
        #pragma unroll
        for (int c = 1; c < Cc; ++c) mx = fmaxf(mx, lg[c]);
        float se = 0.0f;
        #pragma unroll
        for (int c = 0; c < Cc; ++c) { lg[c] = EXP2((lg[c] - mx) * 1.4426950408889634f); se += lg[c]; }
        float inv = RCP(se);
        #pragma unroll
        for (int c = 0; c < Cc; ++c) out[b * Cc + c] = lg[c] * inv;
    }
}

extern "C" void kernel_launch(void* const* d_in, const int* in_sizes, int n_in,
                              void* d_out, int out_size, void* d_ws, size_t ws_size,
                              hipStream_t stream) {
    const float* a0       = (const float*)d_in[0];
    const float* a1       = (const float*)d_in[1];
    const float* a2       = (const float*)d_in[2];
    const float* rnn1_wih = (const float*)d_in[3];
    const float* rnn1_whh = (const float*)d_in[4];
    const float* rnn1_bih = (const float*)d_in[5];
    const float* rnn1_bhh = (const float*)d_in[6];
    const float* conv_w   = (const float*)d_in[7];
    const float* conv_b   = (const float*)d_in[8];
    const float* rnn2_wih = (const float*)d_in[9];
    const float* rnn2_whh = (const float*)d_in[10];
    const float* rnn2_bih = (const float*)d_in[11];
    const float* rnn2_bhh = (const float*)d_in[12];
    const float* gamma    = (const float*)d_in[13];
    const float* beta     = (const float*)d_in[14];
    const float* fnn_w    = (const float*)d_in[15];
    const float* fnn_b    = (const float*)d_in[16];

    float* out = (float*)d_out;

    // workspace layout
    char* ws = (char*)d_ws;
    unsigned short* fusion = (unsigned short*)ws;              // M*BE bf16 = 4 MB
    float* stats = (float*)(ws + (size_t)Mm * BE * 2);         // 512 floats
    float* feat  = stats + 512;                                // BE floats

    k_rnn1<<<NTOT / 2 / 256, 256, 0, stream>>>(a0, a1, a2,
        rnn1_wih, rnn1_whh, rnn1_bih, rnn1_bhh, conv_w, conv_b,
        fusion, stats);
    k_rnn2<<<Bb, 256, 0, stream>>>(fusion,
        rnn2_wih, rnn2_whh, rnn2_bih, rnn2_bhh, feat, stats);
    k_head<<<Bb, 256, 0, stream>>>(feat, stats,
        gamma, beta, fnn_w, fnn_b, out);
}